// Round 3
// baseline (935.803 us; speedup 1.0000x reference)
//
#include <hip/hip_runtime.h>
#include <math.h>

#define EPSF 1e-8f

// acc doubles in workspace, padded onto separate cache lines
#define ACC_MIN 0
#define ACC_VAR 16
#define ACC_NRM 32

// ---------------------------------------------------------------------------
// block reduction helper: wave64 shuffle + LDS + double atomics
// ---------------------------------------------------------------------------
__device__ __forceinline__ void block_reduce_atomic3(
    float a, float b, float c, double* acc)
{
    #pragma unroll
    for (int off = 32; off > 0; off >>= 1) {
        a += __shfl_down(a, off);
        b += __shfl_down(b, off);
        c += __shfl_down(c, off);
    }
    __shared__ float red[3][4];
    const int lane = threadIdx.x & 63;
    const int wave = threadIdx.x >> 6;
    if (lane == 0) { red[0][wave] = a; red[1][wave] = b; red[2][wave] = c; }
    __syncthreads();
    if (threadIdx.x == 0) {
        double x = 0, y = 0, z = 0;
        #pragma unroll
        for (int wv = 0; wv < 4; ++wv) { x += red[0][wv]; y += red[1][wv]; z += red[2][wv]; }
        if (x != 0.0) atomicAdd(&acc[ACC_MIN], x);
        if (y != 0.0) atomicAdd(&acc[ACC_VAR], y);
        if (z != 0.0) atomicAdd(&acc[ACC_NRM], z);
    }
}

// ---------------------------------------------------------------------------
// per-point streaming math (shared by prepass and fallback)
// returns s_min contribution, s_nrm contribution, nhat + pdotn
// ---------------------------------------------------------------------------
__device__ __forceinline__ void point_stream_math(
    float px, float py, float pz,
    float nx, float ny, float nz,
    float s0, float s1, float s2,
    float qw, float qx, float qy, float qz,
    float& out_min, float& out_nrm,
    float& onx, float& ony, float& onz, float& opd)
{
    const float ninv = 1.f / (sqrtf(nx*nx + ny*ny + nz*nz) + EPSF);
    nx *= ninv; ny *= ninv; nz *= ninv;

    out_min = fminf(s0, fminf(s1, s2));
    const int min_idx = (s0 <= s1 && s0 <= s2) ? 0 : ((s1 <= s2) ? 1 : 2);

    const float qinv = 1.f / (sqrtf(qw*qw + qx*qx + qy*qy + qz*qz) + EPSF);
    const float w = qw*qinv, x = qx*qinv, y = qy*qinv, z = qz*qinv;
    float ax, ay, az;
    if (min_idx == 0) {
        ax = 1.f - 2.f*(y*y + z*z); ay = 2.f*(x*y + w*z); az = 2.f*(x*z - w*y);
    } else if (min_idx == 1) {
        ax = 2.f*(x*y - w*z); ay = 1.f - 2.f*(x*x + z*z); az = 2.f*(y*z + w*x);
    } else {
        ax = 2.f*(x*z + w*y); ay = 2.f*(y*z - w*x); az = 1.f - 2.f*(x*x + y*y);
    }
    out_nrm = 1.f - fabsf(ax*nx + ay*ny + az*nz);

    onx = nx; ony = ny; onz = nz;
    opd = px*nx + py*ny + pz*nz;
}

// ---------------------------------------------------------------------------
// Prepass: pack xyz -> float4 (16B aligned gather target),
// nhat4 = (n̂x, n̂y, n̂z, p·n̂), and accumulate loss_size / loss_normal sums.
// 4 points per thread, fully vectorized float4 streaming reads.
// ---------------------------------------------------------------------------
__global__ __launch_bounds__(256) void align_pack(
    const float* __restrict__ xyz,
    const float* __restrict__ scales,
    const float* __restrict__ rotation,
    const float* __restrict__ normal,
    float4* __restrict__ xyz4,
    float4* __restrict__ nhat4,
    double* __restrict__ acc,
    int n)
{
    float s_min = 0.f, s_nrm = 0.f;
    const int ntask = n >> 2;              // 4 points per task
    const int stride = gridDim.x * blockDim.x;
    const int tid0 = blockIdx.x * blockDim.x + threadIdx.x;

    for (int tsk = tid0; tsk < ntask; tsk += stride) {
        const int i0 = tsk * 4;
        // 12 floats = 4 points, 16B-aligned (48B per task)
        const float4* xv = (const float4*)(xyz    + (size_t)i0*3);
        const float4* sv = (const float4*)(scales + (size_t)i0*3);
        const float4* nv = (const float4*)(normal + (size_t)i0*3);
        const float4* qv = (const float4*)(rotation + (size_t)i0*4);
        const float4 xa = xv[0], xb = xv[1], xc = xv[2];
        const float4 sa = sv[0], sb = sv[1], sc = sv[2];
        const float4 na = nv[0], nb = nv[1], nc4 = nv[2];

        const float PX[4] = {xa.x, xa.w, xb.z, xc.y};
        const float PY[4] = {xa.y, xb.x, xb.w, xc.z};
        const float PZ[4] = {xa.z, xb.y, xc.x, xc.w};
        const float S0[4] = {sa.x, sa.w, sb.z, sc.y};
        const float S1[4] = {sa.y, sb.x, sb.w, sc.z};
        const float S2[4] = {sa.z, sb.y, sc.x, sc.w};
        const float NX[4] = {na.x, na.w, nb.z, nc4.y};
        const float NY[4] = {na.y, nb.x, nb.w, nc4.z};
        const float NZ[4] = {na.z, nb.y, nc4.x, nc4.w};

        #pragma unroll
        for (int m = 0; m < 4; ++m) {
            const float4 q = qv[m];
            float omin, onrm, nx, ny, nz, pd;
            point_stream_math(PX[m], PY[m], PZ[m], NX[m], NY[m], NZ[m],
                              S0[m], S1[m], S2[m], q.x, q.y, q.z, q.w,
                              omin, onrm, nx, ny, nz, pd);
            s_min += omin; s_nrm += onrm;
            xyz4[i0 + m]  = make_float4(PX[m], PY[m], PZ[m], 0.f);
            nhat4[i0 + m] = make_float4(nx, ny, nz, pd);
        }
    }

    // scalar tail (n not divisible by 4) — done by global thread 0
    if (tid0 == 0) {
        for (int i = ntask*4; i < n; ++i) {
            float omin, onrm, nx, ny, nz, pd;
            point_stream_math(xyz[3*(size_t)i], xyz[3*(size_t)i+1], xyz[3*(size_t)i+2],
                              normal[3*(size_t)i], normal[3*(size_t)i+1], normal[3*(size_t)i+2],
                              scales[3*(size_t)i], scales[3*(size_t)i+1], scales[3*(size_t)i+2],
                              rotation[4*(size_t)i], rotation[4*(size_t)i+1],
                              rotation[4*(size_t)i+2], rotation[4*(size_t)i+3],
                              omin, onrm, nx, ny, nz, pd);
            s_min += omin; s_nrm += onrm;
            xyz4[i]  = make_float4(xyz[3*(size_t)i], xyz[3*(size_t)i+1], xyz[3*(size_t)i+2], 0.f);
            nhat4[i] = make_float4(nx, ny, nz, pd);
        }
    }

    block_reduce_atomic3(s_min, 0.f, s_nrm, acc);
}

// ---------------------------------------------------------------------------
// Gather kernel: persistent, fully-resident grid (1024 blocks, 4/CU).
// Each thread owns 2 consecutive points per sweep; their 32 knn indices stay
// in VGPRs. Chunk loop (idx>>cshift == c) keeps the 2MB gather slice
// L2-resident; all blocks start together and run identical trip counts,
// so chunk phases stay aligned across the XCD.
// ---------------------------------------------------------------------------
__device__ __forceinline__ void proc_gather(
    int j, int c, int cshift, const float4 nh,
    float& sd, float& sq, const float4* __restrict__ xyz4)
{
    if ((j >> cshift) == c) {
        const float4 v = xyz4[j];
        const float d = v.x*nh.x + v.y*nh.y + v.z*nh.z - nh.w;
        sd += d; sq += d*d;
    }
}

__global__ __launch_bounds__(256, 4) void align_gather(
    const float4* __restrict__ xyz4,
    const float4* __restrict__ nhat4,
    const int*   __restrict__ knn,
    double* __restrict__ acc,
    int n, int cshift, int nc)
{
    float s_var = 0.f;
    const int tid = blockIdx.x * blockDim.x + threadIdx.x;
    const int T = gridDim.x * blockDim.x;
    const int per_sweep = T * 2;
    const int ngroups = (n + per_sweep - 1) / per_sweep;

    for (int g = 0; g < ngroups; ++g) {
        const int p0 = g * per_sweep + tid * 2;
        const int p1 = p0 + 1;
        const bool v0 = p0 < n, v1 = p1 < n;

        const float4 nh0 = v0 ? nhat4[p0] : make_float4(0,0,0,0);
        const float4 nh1 = v1 ? nhat4[p1] : make_float4(0,0,0,0);

        int4 I0[4], I1[4];
        const int4 inval = make_int4(-1,-1,-1,-1);   // -1>>s == -1, never matches
        if (v0) {
            const int4* r = (const int4*)(knn + (size_t)p0 * 16);
            I0[0]=r[0]; I0[1]=r[1]; I0[2]=r[2]; I0[3]=r[3];
        } else { I0[0]=inval; I0[1]=inval; I0[2]=inval; I0[3]=inval; }
        if (v1) {
            const int4* r = (const int4*)(knn + (size_t)p1 * 16);
            I1[0]=r[0]; I1[1]=r[1]; I1[2]=r[2]; I1[3]=r[3];
        } else { I1[0]=inval; I1[1]=inval; I1[2]=inval; I1[3]=inval; }

        float sd0 = 0.f, sq0 = 0.f, sd1 = 0.f, sq1 = 0.f;

        for (int c = 0; c < nc; ++c) {
            #pragma unroll
            for (int q = 0; q < 4; ++q) {
                proc_gather(I0[q].x, c, cshift, nh0, sd0, sq0, xyz4);
                proc_gather(I0[q].y, c, cshift, nh0, sd0, sq0, xyz4);
                proc_gather(I0[q].z, c, cshift, nh0, sd0, sq0, xyz4);
                proc_gather(I0[q].w, c, cshift, nh0, sd0, sq0, xyz4);
                proc_gather(I1[q].x, c, cshift, nh1, sd1, sq1, xyz4);
                proc_gather(I1[q].y, c, cshift, nh1, sd1, sq1, xyz4);
                proc_gather(I1[q].z, c, cshift, nh1, sd1, sq1, xyz4);
                proc_gather(I1[q].w, c, cshift, nh1, sd1, sq1, xyz4);
            }
        }
        if (v0) s_var += sq0 - sd0 * sd0 * (1.f/16.f);
        if (v1) s_var += sq1 - sd1 * sd1 * (1.f/16.f);
    }

    block_reduce_atomic3(0.f, s_var, 0.f, acc);
}

// ---------------------------------------------------------------------------
// Fallback: known-good monolithic kernel (round 2) if ws too small
// ---------------------------------------------------------------------------
__global__ __launch_bounds__(256) void align_direct(
    const float* __restrict__ xyz,
    const float* __restrict__ scales,
    const float* __restrict__ rotation,
    const int*   __restrict__ knn,
    const float* __restrict__ normal,
    double* __restrict__ acc,
    int n)
{
    float s_min = 0.f, s_var = 0.f, s_nrm = 0.f;
    const int stride = gridDim.x * blockDim.x;
    for (int i = blockIdx.x * blockDim.x + threadIdx.x; i < n; i += stride) {
        float omin, onrm, nx, ny, nz, pd;
        point_stream_math(xyz[3*(size_t)i], xyz[3*(size_t)i+1], xyz[3*(size_t)i+2],
                          normal[3*(size_t)i], normal[3*(size_t)i+1], normal[3*(size_t)i+2],
                          scales[3*(size_t)i], scales[3*(size_t)i+1], scales[3*(size_t)i+2],
                          rotation[4*(size_t)i], rotation[4*(size_t)i+1],
                          rotation[4*(size_t)i+2], rotation[4*(size_t)i+3],
                          omin, onrm, nx, ny, nz, pd);
        s_min += omin; s_nrm += onrm;

        const int4* krow = (const int4*)(knn + (size_t)16 * i);
        float sum_d = 0.f, sum_d2 = 0.f;
        #pragma unroll
        for (int q = 0; q < 4; ++q) {
            const int4 j4 = krow[q];
            const int js[4] = { j4.x, j4.y, j4.z, j4.w };
            #pragma unroll
            for (int t = 0; t < 4; ++t) {
                const size_t j = (size_t)js[t] * 3;
                const float d = xyz[j]*nx + xyz[j+1]*ny + xyz[j+2]*nz - pd;
                sum_d  += d; sum_d2 += d*d;
            }
        }
        s_var += sum_d2 - sum_d * sum_d * (1.f/16.f);
    }
    block_reduce_atomic3(s_min, s_var, s_nrm, acc);
}

__global__ void align_finalize(const double* __restrict__ acc,
                               float* __restrict__ out, int n)
{
    if (threadIdx.x == 0) {
        out[0] = (float)(acc[ACC_MIN] / (double)n);
        out[1] = (float)(acc[ACC_VAR] / ((double)n * 16.0));
        out[2] = (float)(acc[ACC_NRM] / (double)n);
    }
}

extern "C" void kernel_launch(void* const* d_in, const int* in_sizes, int n_in,
                              void* d_out, int out_size, void* d_ws, size_t ws_size,
                              hipStream_t stream) {
    const float* xyz      = (const float*)d_in[0];
    const float* scales   = (const float*)d_in[2];
    const float* rotation = (const float*)d_in[3];
    const int*   knn      = (const int*)d_in[4];
    const float* normal   = (const float*)d_in[5];
    float* out = (float*)d_out;

    const int n = in_sizes[1];  // xyz_id count == N

    const size_t need = (size_t)n * 32 + 64 * sizeof(double);
    if (ws_size >= need) {
        float4* xyz4  = (float4*)d_ws;
        float4* nhat4 = (float4*)((char*)d_ws + (size_t)n * 16);
        double* acc   = (double*)((char*)d_ws + (size_t)n * 32);

        hipMemsetAsync(acc, 0, 33 * sizeof(double), stream);

        const int ntask = n >> 2;
        int pgrid = (ntask + 255) / 256;
        if (pgrid > 2048) pgrid = 2048;
        align_pack<<<pgrid, 256, 0, stream>>>(xyz, scales, rotation, normal,
                                              xyz4, nhat4, acc, n);

        int cshift = 17;                      // 2MB float4 chunks
        while (((n - 1) >> cshift) > 15) cshift++;
        const int nc = ((n - 1) >> cshift) + 1;

        align_gather<<<1024, 256, 0, stream>>>(xyz4, nhat4, knn, acc, n, cshift, nc);
        align_finalize<<<1, 64, 0, stream>>>(acc, out, n);
    } else {
        double* acc = (double*)d_ws;
        hipMemsetAsync(acc, 0, 33 * sizeof(double), stream);
        int grid = (n + 255) / 256;
        if (grid > 2048) grid = 2048;
        align_direct<<<grid, 256, 0, stream>>>(xyz, scales, rotation, knn, normal, acc, n);
        align_finalize<<<1, 64, 0, stream>>>(acc, out, n);
    }
}

// Round 4
// 786.590 us; speedup vs baseline: 1.1897x; 1.1897x over previous
//
#include <hip/hip_runtime.h>
#include <math.h>

#define EPSF 1e-8f

// acc doubles in workspace, padded onto separate cache lines
#define ACC_MIN 0
#define ACC_VAR 16
#define ACC_NRM 32

typedef int   v4i __attribute__((ext_vector_type(4)));
typedef float v4f __attribute__((ext_vector_type(4)));

// ---------------------------------------------------------------------------
// block reduction helper: wave64 shuffle + LDS + double atomics
// ---------------------------------------------------------------------------
__device__ __forceinline__ void block_reduce_atomic3(
    float a, float b, float c, double* acc)
{
    #pragma unroll
    for (int off = 32; off > 0; off >>= 1) {
        a += __shfl_down(a, off);
        b += __shfl_down(b, off);
        c += __shfl_down(c, off);
    }
    __shared__ float red[3][4];
    const int lane = threadIdx.x & 63;
    const int wave = threadIdx.x >> 6;
    if (lane == 0) { red[0][wave] = a; red[1][wave] = b; red[2][wave] = c; }
    __syncthreads();
    if (threadIdx.x == 0) {
        double x = 0, y = 0, z = 0;
        #pragma unroll
        for (int wv = 0; wv < 4; ++wv) { x += red[0][wv]; y += red[1][wv]; z += red[2][wv]; }
        if (x != 0.0) atomicAdd(&acc[ACC_MIN], x);
        if (y != 0.0) atomicAdd(&acc[ACC_VAR], y);
        if (z != 0.0) atomicAdd(&acc[ACC_NRM], z);
    }
}

// ---------------------------------------------------------------------------
// per-point streaming math
// ---------------------------------------------------------------------------
__device__ __forceinline__ void point_stream_math(
    float px, float py, float pz,
    float nx, float ny, float nz,
    float s0, float s1, float s2,
    float qw, float qx, float qy, float qz,
    float& out_min, float& out_nrm,
    float& onx, float& ony, float& onz, float& opd)
{
    const float ninv = 1.f / (sqrtf(nx*nx + ny*ny + nz*nz) + EPSF);
    nx *= ninv; ny *= ninv; nz *= ninv;

    out_min = fminf(s0, fminf(s1, s2));
    const int min_idx = (s0 <= s1 && s0 <= s2) ? 0 : ((s1 <= s2) ? 1 : 2);

    const float qinv = 1.f / (sqrtf(qw*qw + qx*qx + qy*qy + qz*qz) + EPSF);
    const float w = qw*qinv, x = qx*qinv, y = qy*qinv, z = qz*qinv;
    float ax, ay, az;
    if (min_idx == 0) {
        ax = 1.f - 2.f*(y*y + z*z); ay = 2.f*(x*y + w*z); az = 2.f*(x*z - w*y);
    } else if (min_idx == 1) {
        ax = 2.f*(x*y - w*z); ay = 1.f - 2.f*(x*x + z*z); az = 2.f*(y*z + w*x);
    } else {
        ax = 2.f*(x*z + w*y); ay = 2.f*(y*z - w*x); az = 1.f - 2.f*(x*x + y*y);
    }
    out_nrm = 1.f - fabsf(ax*nx + ay*ny + az*nz);

    onx = nx; ony = ny; onz = nz;
    opd = px*nx + py*ny + pz*nz;
}

// ---------------------------------------------------------------------------
// Prepass: pack xyz -> float4, nhat4 = (n̂, p·n̂), accumulate size/normal sums
// ---------------------------------------------------------------------------
__global__ __launch_bounds__(256) void align_pack(
    const float* __restrict__ xyz,
    const float* __restrict__ scales,
    const float* __restrict__ rotation,
    const float* __restrict__ normal,
    float4* __restrict__ xyz4,
    float4* __restrict__ nhat4,
    double* __restrict__ acc,
    int n)
{
    float s_min = 0.f, s_nrm = 0.f;
    const int ntask = n >> 2;              // 4 points per task
    const int stride = gridDim.x * blockDim.x;
    const int tid0 = blockIdx.x * blockDim.x + threadIdx.x;

    for (int tsk = tid0; tsk < ntask; tsk += stride) {
        const int i0 = tsk * 4;
        const float4* xv = (const float4*)(xyz    + (size_t)i0*3);
        const float4* sv = (const float4*)(scales + (size_t)i0*3);
        const float4* nv = (const float4*)(normal + (size_t)i0*3);
        const float4* qv = (const float4*)(rotation + (size_t)i0*4);
        const float4 xa = xv[0], xb = xv[1], xc = xv[2];
        const float4 sa = sv[0], sb = sv[1], sc = sv[2];
        const float4 na = nv[0], nb = nv[1], nc4 = nv[2];

        const float PX[4] = {xa.x, xa.w, xb.z, xc.y};
        const float PY[4] = {xa.y, xb.x, xb.w, xc.z};
        const float PZ[4] = {xa.z, xb.y, xc.x, xc.w};
        const float S0[4] = {sa.x, sa.w, sb.z, sc.y};
        const float S1[4] = {sa.y, sb.x, sb.w, sc.z};
        const float S2[4] = {sa.z, sb.y, sc.x, sc.w};
        const float NX[4] = {na.x, na.w, nb.z, nc4.y};
        const float NY[4] = {na.y, nb.x, nb.w, nc4.z};
        const float NZ[4] = {na.z, nb.y, nc4.x, nc4.w};

        #pragma unroll
        for (int m = 0; m < 4; ++m) {
            const float4 q = qv[m];
            float omin, onrm, nx, ny, nz, pd;
            point_stream_math(PX[m], PY[m], PZ[m], NX[m], NY[m], NZ[m],
                              S0[m], S1[m], S2[m], q.x, q.y, q.z, q.w,
                              omin, onrm, nx, ny, nz, pd);
            s_min += omin; s_nrm += onrm;
            xyz4[i0 + m]  = make_float4(PX[m], PY[m], PZ[m], 0.f);
            nhat4[i0 + m] = make_float4(nx, ny, nz, pd);
        }
    }

    // scalar tail (n not divisible by 4)
    if (tid0 == 0) {
        for (int i = ntask*4; i < n; ++i) {
            float omin, onrm, nx, ny, nz, pd;
            point_stream_math(xyz[3*(size_t)i], xyz[3*(size_t)i+1], xyz[3*(size_t)i+2],
                              normal[3*(size_t)i], normal[3*(size_t)i+1], normal[3*(size_t)i+2],
                              scales[3*(size_t)i], scales[3*(size_t)i+1], scales[3*(size_t)i+2],
                              rotation[4*(size_t)i], rotation[4*(size_t)i+1],
                              rotation[4*(size_t)i+2], rotation[4*(size_t)i+3],
                              omin, onrm, nx, ny, nz, pd);
            s_min += omin; s_nrm += onrm;
            xyz4[i]  = make_float4(xyz[3*(size_t)i], xyz[3*(size_t)i+1], xyz[3*(size_t)i+2], 0.f);
            nhat4[i] = make_float4(nx, ny, nz, pd);
        }
    }

    block_reduce_atomic3(s_min, 0.f, s_nrm, acc);
}

// ---------------------------------------------------------------------------
// Gather kernel: flat (no chunking, no occupancy cap). 2 points per thread.
// Each neighbor = ONE aligned global_load_dwordx4 from the packed xyz4.
// knn / nhat4 streamed nontemporally so the L2 stays dedicated to xyz4.
// All 16 gathers per point are independent -> deep vmcnt pipelining.
// ---------------------------------------------------------------------------
__global__ __launch_bounds__(256) void align_gather2(
    const float4* __restrict__ xyz4,
    const float4* __restrict__ nhat4,
    const int*   __restrict__ knn,
    double* __restrict__ acc,
    int n)
{
    const int t = blockIdx.x * blockDim.x + threadIdx.x;
    float s_var = 0.f;

    #pragma unroll
    for (int p = 0; p < 2; ++p) {
        const int i = t * 2 + p;
        if (i < n) {
            const v4f nh = __builtin_nontemporal_load((const v4f*)(nhat4 + i));
            const v4i* kr = (const v4i*)(knn + (size_t)i * 16);
            const v4i I0 = __builtin_nontemporal_load(kr + 0);
            const v4i I1 = __builtin_nontemporal_load(kr + 1);
            const v4i I2 = __builtin_nontemporal_load(kr + 2);
            const v4i I3 = __builtin_nontemporal_load(kr + 3);
            const int idx[16] = {I0.x, I0.y, I0.z, I0.w,
                                 I1.x, I1.y, I1.z, I1.w,
                                 I2.x, I2.y, I2.z, I2.w,
                                 I3.x, I3.y, I3.z, I3.w};
            v4f P[16];
            #pragma unroll
            for (int k = 0; k < 16; ++k)
                P[k] = *(const v4f*)(xyz4 + (size_t)idx[k]);   // cached (L2-friendly)

            float sd = 0.f, sq = 0.f;
            #pragma unroll
            for (int k = 0; k < 16; ++k) {
                const float d = P[k].x*nh.x + P[k].y*nh.y + P[k].z*nh.z - nh.w;
                sd += d; sq += d*d;
            }
            s_var += sq - sd * sd * (1.f/16.f);
        }
    }

    block_reduce_atomic3(0.f, s_var, 0.f, acc);
}

// ---------------------------------------------------------------------------
// Fallback: known-good monolithic kernel (round 2) if ws too small
// ---------------------------------------------------------------------------
__global__ __launch_bounds__(256) void align_direct(
    const float* __restrict__ xyz,
    const float* __restrict__ scales,
    const float* __restrict__ rotation,
    const int*   __restrict__ knn,
    const float* __restrict__ normal,
    double* __restrict__ acc,
    int n)
{
    float s_min = 0.f, s_var = 0.f, s_nrm = 0.f;
    const int stride = gridDim.x * blockDim.x;
    for (int i = blockIdx.x * blockDim.x + threadIdx.x; i < n; i += stride) {
        float omin, onrm, nx, ny, nz, pd;
        point_stream_math(xyz[3*(size_t)i], xyz[3*(size_t)i+1], xyz[3*(size_t)i+2],
                          normal[3*(size_t)i], normal[3*(size_t)i+1], normal[3*(size_t)i+2],
                          scales[3*(size_t)i], scales[3*(size_t)i+1], scales[3*(size_t)i+2],
                          rotation[4*(size_t)i], rotation[4*(size_t)i+1],
                          rotation[4*(size_t)i+2], rotation[4*(size_t)i+3],
                          omin, onrm, nx, ny, nz, pd);
        s_min += omin; s_nrm += onrm;

        const int4* krow = (const int4*)(knn + (size_t)16 * i);
        float sum_d = 0.f, sum_d2 = 0.f;
        #pragma unroll
        for (int q = 0; q < 4; ++q) {
            const int4 j4 = krow[q];
            const int js[4] = { j4.x, j4.y, j4.z, j4.w };
            #pragma unroll
            for (int u = 0; u < 4; ++u) {
                const size_t j = (size_t)js[u] * 3;
                const float d = xyz[j]*nx + xyz[j+1]*ny + xyz[j+2]*nz - pd;
                sum_d  += d; sum_d2 += d*d;
            }
        }
        s_var += sum_d2 - sum_d * sum_d * (1.f/16.f);
    }
    block_reduce_atomic3(s_min, s_var, s_nrm, acc);
}

__global__ void align_finalize(const double* __restrict__ acc,
                               float* __restrict__ out, int n)
{
    if (threadIdx.x == 0) {
        out[0] = (float)(acc[ACC_MIN] / (double)n);
        out[1] = (float)(acc[ACC_VAR] / ((double)n * 16.0));
        out[2] = (float)(acc[ACC_NRM] / (double)n);
    }
}

extern "C" void kernel_launch(void* const* d_in, const int* in_sizes, int n_in,
                              void* d_out, int out_size, void* d_ws, size_t ws_size,
                              hipStream_t stream) {
    const float* xyz      = (const float*)d_in[0];
    const float* scales   = (const float*)d_in[2];
    const float* rotation = (const float*)d_in[3];
    const int*   knn      = (const int*)d_in[4];
    const float* normal   = (const float*)d_in[5];
    float* out = (float*)d_out;

    const int n = in_sizes[1];  // xyz_id count == N

    const size_t need = (size_t)n * 32 + 64 * sizeof(double);
    if (ws_size >= need) {
        float4* xyz4  = (float4*)d_ws;
        float4* nhat4 = (float4*)((char*)d_ws + (size_t)n * 16);
        double* acc   = (double*)((char*)d_ws + (size_t)n * 32);

        hipMemsetAsync(acc, 0, 33 * sizeof(double), stream);

        const int ntask = n >> 2;
        int pgrid = (ntask + 255) / 256;
        if (pgrid > 2048) pgrid = 2048;
        align_pack<<<pgrid, 256, 0, stream>>>(xyz, scales, rotation, normal,
                                              xyz4, nhat4, acc, n);

        const int ggrid = (n + 511) / 512;   // 2 points per thread
        align_gather2<<<ggrid, 256, 0, stream>>>(xyz4, nhat4, knn, acc, n);
        align_finalize<<<1, 64, 0, stream>>>(acc, out, n);
    } else {
        double* acc = (double*)d_ws;
        hipMemsetAsync(acc, 0, 33 * sizeof(double), stream);
        int grid = (n + 255) / 256;
        if (grid > 2048) grid = 2048;
        align_direct<<<grid, 256, 0, stream>>>(xyz, scales, rotation, knn, normal, acc, n);
        align_finalize<<<1, 64, 0, stream>>>(acc, out, n);
    }
}

// Round 5
// 722.590 us; speedup vs baseline: 1.2951x; 1.0886x over previous
//
#include <hip/hip_runtime.h>
#include <math.h>

#define EPSF 1e-8f

// acc doubles in workspace, padded onto separate cache lines
#define ACC_MIN 0
#define ACC_VAR 16
#define ACC_NRM 32

typedef int      v4i __attribute__((ext_vector_type(4)));
typedef float    v4f __attribute__((ext_vector_type(4)));
typedef _Float16 h4  __attribute__((ext_vector_type(4)));

// ---------------------------------------------------------------------------
// block reduction helper: wave64 shuffle + LDS + double atomics
// ---------------------------------------------------------------------------
__device__ __forceinline__ void block_reduce_atomic3(
    float a, float b, float c, double* acc)
{
    #pragma unroll
    for (int off = 32; off > 0; off >>= 1) {
        a += __shfl_down(a, off);
        b += __shfl_down(b, off);
        c += __shfl_down(c, off);
    }
    __shared__ float red[3][4];
    const int lane = threadIdx.x & 63;
    const int wave = threadIdx.x >> 6;
    if (lane == 0) { red[0][wave] = a; red[1][wave] = b; red[2][wave] = c; }
    __syncthreads();
    if (threadIdx.x == 0) {
        double x = 0, y = 0, z = 0;
        #pragma unroll
        for (int wv = 0; wv < 4; ++wv) { x += red[0][wv]; y += red[1][wv]; z += red[2][wv]; }
        if (x != 0.0) atomicAdd(&acc[ACC_MIN], x);
        if (y != 0.0) atomicAdd(&acc[ACC_VAR], y);
        if (z != 0.0) atomicAdd(&acc[ACC_NRM], z);
    }
}

// ---------------------------------------------------------------------------
// per-point streaming math
// ---------------------------------------------------------------------------
__device__ __forceinline__ void point_stream_math(
    float px, float py, float pz,
    float nx, float ny, float nz,
    float s0, float s1, float s2,
    float qw, float qx, float qy, float qz,
    float& out_min, float& out_nrm,
    float& onx, float& ony, float& onz, float& opd)
{
    const float ninv = 1.f / (sqrtf(nx*nx + ny*ny + nz*nz) + EPSF);
    nx *= ninv; ny *= ninv; nz *= ninv;

    out_min = fminf(s0, fminf(s1, s2));
    const int min_idx = (s0 <= s1 && s0 <= s2) ? 0 : ((s1 <= s2) ? 1 : 2);

    const float qinv = 1.f / (sqrtf(qw*qw + qx*qx + qy*qy + qz*qz) + EPSF);
    const float w = qw*qinv, x = qx*qinv, y = qy*qinv, z = qz*qinv;
    float ax, ay, az;
    if (min_idx == 0) {
        ax = 1.f - 2.f*(y*y + z*z); ay = 2.f*(x*y + w*z); az = 2.f*(x*z - w*y);
    } else if (min_idx == 1) {
        ax = 2.f*(x*y - w*z); ay = 1.f - 2.f*(x*x + z*z); az = 2.f*(y*z + w*x);
    } else {
        ax = 2.f*(x*z + w*y); ay = 2.f*(y*z - w*x); az = 1.f - 2.f*(x*x + y*y);
    }
    out_nrm = 1.f - fabsf(ax*nx + ay*ny + az*nz);

    onx = nx; ony = ny; onz = nz;
    opd = px*nx + py*ny + pz*nz;
}

// ---------------------------------------------------------------------------
// Prepass: pack xyz -> f16x4 (8B gather target), nhat4 = (n̂, p·n̂),
// accumulate loss_size / loss_normal sums.
// ---------------------------------------------------------------------------
__global__ __launch_bounds__(256) void align_pack(
    const float* __restrict__ xyz,
    const float* __restrict__ scales,
    const float* __restrict__ rotation,
    const float* __restrict__ normal,
    h4*     __restrict__ xyzh,
    float4* __restrict__ nhat4,
    double* __restrict__ acc,
    int n)
{
    float s_min = 0.f, s_nrm = 0.f;
    const int ntask = n >> 2;              // 4 points per task
    const int stride = gridDim.x * blockDim.x;
    const int tid0 = blockIdx.x * blockDim.x + threadIdx.x;

    for (int tsk = tid0; tsk < ntask; tsk += stride) {
        const int i0 = tsk * 4;
        const float4* xv = (const float4*)(xyz    + (size_t)i0*3);
        const float4* sv = (const float4*)(scales + (size_t)i0*3);
        const float4* nv = (const float4*)(normal + (size_t)i0*3);
        const float4* qv = (const float4*)(rotation + (size_t)i0*4);
        const float4 xa = xv[0], xb = xv[1], xc = xv[2];
        const float4 sa = sv[0], sb = sv[1], sc = sv[2];
        const float4 na = nv[0], nb = nv[1], nc4 = nv[2];

        const float PX[4] = {xa.x, xa.w, xb.z, xc.y};
        const float PY[4] = {xa.y, xb.x, xb.w, xc.z};
        const float PZ[4] = {xa.z, xb.y, xc.x, xc.w};
        const float S0[4] = {sa.x, sa.w, sb.z, sc.y};
        const float S1[4] = {sa.y, sb.x, sb.w, sc.z};
        const float S2[4] = {sa.z, sb.y, sc.x, sc.w};
        const float NX[4] = {na.x, na.w, nb.z, nc4.y};
        const float NY[4] = {na.y, nb.x, nb.w, nc4.z};
        const float NZ[4] = {na.z, nb.y, nc4.x, nc4.w};

        #pragma unroll
        for (int m = 0; m < 4; ++m) {
            const float4 q = qv[m];
            float omin, onrm, nx, ny, nz, pd;
            point_stream_math(PX[m], PY[m], PZ[m], NX[m], NY[m], NZ[m],
                              S0[m], S1[m], S2[m], q.x, q.y, q.z, q.w,
                              omin, onrm, nx, ny, nz, pd);
            s_min += omin; s_nrm += onrm;
            h4 hp;
            hp.x = (_Float16)PX[m]; hp.y = (_Float16)PY[m];
            hp.z = (_Float16)PZ[m]; hp.w = (_Float16)0.f;
            xyzh[i0 + m]  = hp;
            nhat4[i0 + m] = make_float4(nx, ny, nz, pd);
        }
    }

    // scalar tail (n not divisible by 4)
    if (tid0 == 0) {
        for (int i = ntask*4; i < n; ++i) {
            float omin, onrm, nx, ny, nz, pd;
            point_stream_math(xyz[3*(size_t)i], xyz[3*(size_t)i+1], xyz[3*(size_t)i+2],
                              normal[3*(size_t)i], normal[3*(size_t)i+1], normal[3*(size_t)i+2],
                              scales[3*(size_t)i], scales[3*(size_t)i+1], scales[3*(size_t)i+2],
                              rotation[4*(size_t)i], rotation[4*(size_t)i+1],
                              rotation[4*(size_t)i+2], rotation[4*(size_t)i+3],
                              omin, onrm, nx, ny, nz, pd);
            s_min += omin; s_nrm += onrm;
            h4 hp;
            hp.x = (_Float16)xyz[3*(size_t)i];
            hp.y = (_Float16)xyz[3*(size_t)i+1];
            hp.z = (_Float16)xyz[3*(size_t)i+2];
            hp.w = (_Float16)0.f;
            xyzh[i]  = hp;
            nhat4[i] = make_float4(nx, ny, nz, pd);
        }
    }

    block_reduce_atomic3(s_min, 0.f, s_nrm, acc);
}

// ---------------------------------------------------------------------------
// Gather kernel: flat, 2 points per thread. Each neighbor = ONE aligned
// 8B global_load_dwordx2 from the packed f16 positions (16MB working set).
// knn / nhat4 streamed nontemporally to keep L2 dedicated to the gather.
// ---------------------------------------------------------------------------
__global__ __launch_bounds__(256) void align_gather2(
    const h4*     __restrict__ xyzh,
    const float4* __restrict__ nhat4,
    const int*    __restrict__ knn,
    double* __restrict__ acc,
    int n)
{
    const int t = blockIdx.x * blockDim.x + threadIdx.x;
    float s_var = 0.f;

    #pragma unroll
    for (int p = 0; p < 2; ++p) {
        const int i = t * 2 + p;
        if (i < n) {
            const v4f nh = __builtin_nontemporal_load((const v4f*)(nhat4 + i));
            const v4i* kr = (const v4i*)(knn + (size_t)i * 16);
            const v4i I0 = __builtin_nontemporal_load(kr + 0);
            const v4i I1 = __builtin_nontemporal_load(kr + 1);
            const v4i I2 = __builtin_nontemporal_load(kr + 2);
            const v4i I3 = __builtin_nontemporal_load(kr + 3);
            const int idx[16] = {I0.x, I0.y, I0.z, I0.w,
                                 I1.x, I1.y, I1.z, I1.w,
                                 I2.x, I2.y, I2.z, I2.w,
                                 I3.x, I3.y, I3.z, I3.w};
            h4 P[16];
            #pragma unroll
            for (int k = 0; k < 16; ++k)
                P[k] = *(const h4*)(xyzh + (size_t)idx[k]);   // 8B cached load

            float sd = 0.f, sq = 0.f;
            #pragma unroll
            for (int k = 0; k < 16; ++k) {
                const float d = (float)P[k].x*nh.x + (float)P[k].y*nh.y
                              + (float)P[k].z*nh.z - nh.w;
                sd += d; sq += d*d;
            }
            s_var += sq - sd * sd * (1.f/16.f);
        }
    }

    block_reduce_atomic3(0.f, s_var, 0.f, acc);
}

// ---------------------------------------------------------------------------
// Fallback: known-good monolithic kernel (round 2) if ws too small
// ---------------------------------------------------------------------------
__global__ __launch_bounds__(256) void align_direct(
    const float* __restrict__ xyz,
    const float* __restrict__ scales,
    const float* __restrict__ rotation,
    const int*   __restrict__ knn,
    const float* __restrict__ normal,
    double* __restrict__ acc,
    int n)
{
    float s_min = 0.f, s_var = 0.f, s_nrm = 0.f;
    const int stride = gridDim.x * blockDim.x;
    for (int i = blockIdx.x * blockDim.x + threadIdx.x; i < n; i += stride) {
        float omin, onrm, nx, ny, nz, pd;
        point_stream_math(xyz[3*(size_t)i], xyz[3*(size_t)i+1], xyz[3*(size_t)i+2],
                          normal[3*(size_t)i], normal[3*(size_t)i+1], normal[3*(size_t)i+2],
                          scales[3*(size_t)i], scales[3*(size_t)i+1], scales[3*(size_t)i+2],
                          rotation[4*(size_t)i], rotation[4*(size_t)i+1],
                          rotation[4*(size_t)i+2], rotation[4*(size_t)i+3],
                          omin, onrm, nx, ny, nz, pd);
        s_min += omin; s_nrm += onrm;

        const int4* krow = (const int4*)(knn + (size_t)16 * i);
        float sum_d = 0.f, sum_d2 = 0.f;
        #pragma unroll
        for (int q = 0; q < 4; ++q) {
            const int4 j4 = krow[q];
            const int js[4] = { j4.x, j4.y, j4.z, j4.w };
            #pragma unroll
            for (int u = 0; u < 4; ++u) {
                const size_t j = (size_t)js[u] * 3;
                const float d = xyz[j]*nx + xyz[j+1]*ny + xyz[j+2]*nz - pd;
                sum_d  += d; sum_d2 += d*d;
            }
        }
        s_var += sum_d2 - sum_d * sum_d * (1.f/16.f);
    }
    block_reduce_atomic3(s_min, s_var, s_nrm, acc);
}

__global__ void align_finalize(const double* __restrict__ acc,
                               float* __restrict__ out, int n)
{
    if (threadIdx.x == 0) {
        out[0] = (float)(acc[ACC_MIN] / (double)n);
        out[1] = (float)(acc[ACC_VAR] / ((double)n * 16.0));
        out[2] = (float)(acc[ACC_NRM] / (double)n);
    }
}

extern "C" void kernel_launch(void* const* d_in, const int* in_sizes, int n_in,
                              void* d_out, int out_size, void* d_ws, size_t ws_size,
                              hipStream_t stream) {
    const float* xyz      = (const float*)d_in[0];
    const float* scales   = (const float*)d_in[2];
    const float* rotation = (const float*)d_in[3];
    const int*   knn      = (const int*)d_in[4];
    const float* normal   = (const float*)d_in[5];
    float* out = (float*)d_out;

    const int n = in_sizes[1];  // xyz_id count == N

    // layout: xyzh (8B*n) | nhat4 (16B*n) | acc (64 doubles)
    const size_t need = (size_t)n * 24 + 64 * sizeof(double);
    if (ws_size >= need) {
        h4*     xyzh  = (h4*)d_ws;
        float4* nhat4 = (float4*)((char*)d_ws + (size_t)n * 8);
        double* acc   = (double*)((char*)d_ws + (size_t)n * 24);

        hipMemsetAsync(acc, 0, 33 * sizeof(double), stream);

        const int ntask = n >> 2;
        int pgrid = (ntask + 255) / 256;
        if (pgrid > 2048) pgrid = 2048;
        align_pack<<<pgrid, 256, 0, stream>>>(xyz, scales, rotation, normal,
                                              xyzh, nhat4, acc, n);

        const int ggrid = (n + 511) / 512;   // 2 points per thread
        align_gather2<<<ggrid, 256, 0, stream>>>(xyzh, nhat4, knn, acc, n);
        align_finalize<<<1, 64, 0, stream>>>(acc, out, n);
    } else {
        double* acc = (double*)d_ws;
        hipMemsetAsync(acc, 0, 33 * sizeof(double), stream);
        int grid = (n + 255) / 256;
        if (grid > 2048) grid = 2048;
        align_direct<<<grid, 256, 0, stream>>>(xyz, scales, rotation, knn, normal, acc, n);
        align_finalize<<<1, 64, 0, stream>>>(acc, out, n);
    }
}

// Round 6
// 544.508 us; speedup vs baseline: 1.7186x; 1.3271x over previous
//
#include <hip/hip_runtime.h>
#include <math.h>

#define EPSF 1e-8f

// acc doubles in workspace, padded onto separate cache lines
#define ACC_MIN 0
#define ACC_VAR 16
#define ACC_NRM 32

typedef int   v4i __attribute__((ext_vector_type(4)));
typedef float v4f __attribute__((ext_vector_type(4)));

// ---------------------------------------------------------------------------
// block reduction helper: wave64 shuffle + LDS + double atomics
// ---------------------------------------------------------------------------
__device__ __forceinline__ void block_reduce_atomic3(
    float a, float b, float c, double* acc)
{
    #pragma unroll
    for (int off = 32; off > 0; off >>= 1) {
        a += __shfl_down(a, off);
        b += __shfl_down(b, off);
        c += __shfl_down(c, off);
    }
    __shared__ float red[3][4];
    const int lane = threadIdx.x & 63;
    const int wave = threadIdx.x >> 6;
    if (lane == 0) { red[0][wave] = a; red[1][wave] = b; red[2][wave] = c; }
    __syncthreads();
    if (threadIdx.x == 0) {
        double x = 0, y = 0, z = 0;
        #pragma unroll
        for (int wv = 0; wv < 4; ++wv) { x += red[0][wv]; y += red[1][wv]; z += red[2][wv]; }
        if (x != 0.0) atomicAdd(&acc[ACC_MIN], x);
        if (y != 0.0) atomicAdd(&acc[ACC_VAR], y);
        if (z != 0.0) atomicAdd(&acc[ACC_NRM], z);
    }
}

// ---------------------------------------------------------------------------
// per-point streaming math
// ---------------------------------------------------------------------------
__device__ __forceinline__ void point_stream_math(
    float px, float py, float pz,
    float nx, float ny, float nz,
    float s0, float s1, float s2,
    float qw, float qx, float qy, float qz,
    float& out_min, float& out_nrm,
    float& onx, float& ony, float& onz, float& opd)
{
    const float ninv = 1.f / (sqrtf(nx*nx + ny*ny + nz*nz) + EPSF);
    nx *= ninv; ny *= ninv; nz *= ninv;

    out_min = fminf(s0, fminf(s1, s2));
    const int min_idx = (s0 <= s1 && s0 <= s2) ? 0 : ((s1 <= s2) ? 1 : 2);

    const float qinv = 1.f / (sqrtf(qw*qw + qx*qx + qy*qy + qz*qz) + EPSF);
    const float w = qw*qinv, x = qx*qinv, y = qy*qinv, z = qz*qinv;
    float ax, ay, az;
    if (min_idx == 0) {
        ax = 1.f - 2.f*(y*y + z*z); ay = 2.f*(x*y + w*z); az = 2.f*(x*z - w*y);
    } else if (min_idx == 1) {
        ax = 2.f*(x*y - w*z); ay = 1.f - 2.f*(x*x + z*z); az = 2.f*(y*z + w*x);
    } else {
        ax = 2.f*(x*z + w*y); ay = 2.f*(y*z - w*x); az = 1.f - 2.f*(x*x + y*y);
    }
    out_nrm = 1.f - fabsf(ax*nx + ay*ny + az*nz);

    onx = nx; ony = ny; onz = nz;
    opd = px*nx + py*ny + pz*nz;
}

__device__ __forceinline__ unsigned quant_point(float px, float py, float pz)
{
    int qx = __float2int_rn(px * 64.f);
    int qy = __float2int_rn(py * 64.f);
    int qz = __float2int_rn(pz * 64.f);
    qx = min(511, max(-512, qx));
    qy = min(511, max(-512, qy));
    qz = min(511, max(-512, qz));
    return (unsigned)(qx & 1023) | ((unsigned)(qy & 1023) << 10)
         | ((unsigned)(qz & 1023) << 20);
}

// ---------------------------------------------------------------------------
// Prepass: quantize xyz -> 10/10/10 fixed point (4B, scale 1/64),
// nhat4 = (n̂/64, p·n̂)  [scale folded into n̂ so gather decode is int cvt+FMA],
// accumulate loss_size / loss_normal sums.
// ---------------------------------------------------------------------------
__global__ __launch_bounds__(256) void align_pack(
    const float* __restrict__ xyz,
    const float* __restrict__ scales,
    const float* __restrict__ rotation,
    const float* __restrict__ normal,
    unsigned* __restrict__ xyzq,
    float4*   __restrict__ nhat4,
    double*   __restrict__ acc,
    int n)
{
    float s_min = 0.f, s_nrm = 0.f;
    const int ntask = n >> 2;              // 4 points per task
    const int stride = gridDim.x * blockDim.x;
    const int tid0 = blockIdx.x * blockDim.x + threadIdx.x;

    for (int tsk = tid0; tsk < ntask; tsk += stride) {
        const int i0 = tsk * 4;
        const float4* xv = (const float4*)(xyz    + (size_t)i0*3);
        const float4* sv = (const float4*)(scales + (size_t)i0*3);
        const float4* nv = (const float4*)(normal + (size_t)i0*3);
        const float4* qv = (const float4*)(rotation + (size_t)i0*4);
        const float4 xa = xv[0], xb = xv[1], xc = xv[2];
        const float4 sa = sv[0], sb = sv[1], sc = sv[2];
        const float4 na = nv[0], nb = nv[1], nc4 = nv[2];

        const float PX[4] = {xa.x, xa.w, xb.z, xc.y};
        const float PY[4] = {xa.y, xb.x, xb.w, xc.z};
        const float PZ[4] = {xa.z, xb.y, xc.x, xc.w};
        const float S0[4] = {sa.x, sa.w, sb.z, sc.y};
        const float S1[4] = {sa.y, sb.x, sb.w, sc.z};
        const float S2[4] = {sa.z, sb.y, sc.x, sc.w};
        const float NX[4] = {na.x, na.w, nb.z, nc4.y};
        const float NY[4] = {na.y, nb.x, nb.w, nc4.z};
        const float NZ[4] = {na.z, nb.y, nc4.x, nc4.w};

        #pragma unroll
        for (int m = 0; m < 4; ++m) {
            const float4 q = qv[m];
            float omin, onrm, nx, ny, nz, pd;
            point_stream_math(PX[m], PY[m], PZ[m], NX[m], NY[m], NZ[m],
                              S0[m], S1[m], S2[m], q.x, q.y, q.z, q.w,
                              omin, onrm, nx, ny, nz, pd);
            s_min += omin; s_nrm += onrm;
            xyzq[i0 + m]  = quant_point(PX[m], PY[m], PZ[m]);
            nhat4[i0 + m] = make_float4(nx * (1.f/64.f), ny * (1.f/64.f),
                                        nz * (1.f/64.f), pd);
        }
    }

    // scalar tail (n not divisible by 4)
    if (tid0 == 0) {
        for (int i = ntask*4; i < n; ++i) {
            float omin, onrm, nx, ny, nz, pd;
            point_stream_math(xyz[3*(size_t)i], xyz[3*(size_t)i+1], xyz[3*(size_t)i+2],
                              normal[3*(size_t)i], normal[3*(size_t)i+1], normal[3*(size_t)i+2],
                              scales[3*(size_t)i], scales[3*(size_t)i+1], scales[3*(size_t)i+2],
                              rotation[4*(size_t)i], rotation[4*(size_t)i+1],
                              rotation[4*(size_t)i+2], rotation[4*(size_t)i+3],
                              omin, onrm, nx, ny, nz, pd);
            s_min += omin; s_nrm += onrm;
            xyzq[i]  = quant_point(xyz[3*(size_t)i], xyz[3*(size_t)i+1], xyz[3*(size_t)i+2]);
            nhat4[i] = make_float4(nx * (1.f/64.f), ny * (1.f/64.f),
                                   nz * (1.f/64.f), pd);
        }
    }

    block_reduce_atomic3(s_min, 0.f, s_nrm, acc);
}

// ---------------------------------------------------------------------------
// Chunked gather: 4 chunks x 2MB, each L2-resident on every XCD.
// 2 points/thread; 32 knn indices live in VGPRs across all chunk passes.
// Flat grid (no occupancy cap); blocks stay naturally in-phase.
// ---------------------------------------------------------------------------
__device__ __forceinline__ void proc_gather_q(
    int j, int c, int cshift, const float4 nh,
    float& sd, float& sq, const unsigned* __restrict__ xyzq)
{
    if ((j >> cshift) == c) {            // -1 padding never matches
        const int w = (int)xyzq[j];
        const float fx = (float)((w << 22) >> 22);
        const float fy = (float)((w << 12) >> 22);
        const float fz = (float)((w <<  2) >> 22);
        const float d = fx*nh.x + fy*nh.y + fz*nh.z - nh.w;
        sd += d; sq += d*d;
    }
}

__global__ __launch_bounds__(256) void align_gather_q(
    const unsigned* __restrict__ xyzq,
    const float4*   __restrict__ nhat4,
    const int*      __restrict__ knn,
    double* __restrict__ acc,
    int n, int cshift, int nc)
{
    const int t = blockIdx.x * blockDim.x + threadIdx.x;
    const int p0 = t * 2;
    const int p1 = p0 + 1;
    const bool v0 = p0 < n, v1 = p1 < n;
    float s_var = 0.f;

    const v4f z4 = {0.f, 0.f, 0.f, 0.f};
    v4f nh0 = z4, nh1 = z4;
    if (v0) nh0 = __builtin_nontemporal_load((const v4f*)(nhat4 + p0));
    if (v1) nh1 = __builtin_nontemporal_load((const v4f*)(nhat4 + p1));
    const float4 NH0 = make_float4(nh0.x, nh0.y, nh0.z, nh0.w);
    const float4 NH1 = make_float4(nh1.x, nh1.y, nh1.z, nh1.w);

    v4i I0[4], I1[4];
    const v4i inval = {-1, -1, -1, -1};
    #pragma unroll
    for (int q = 0; q < 4; ++q) { I0[q] = inval; I1[q] = inval; }
    if (v0) {
        const v4i* r = (const v4i*)(knn + (size_t)p0 * 16);
        I0[0] = __builtin_nontemporal_load(r + 0);
        I0[1] = __builtin_nontemporal_load(r + 1);
        I0[2] = __builtin_nontemporal_load(r + 2);
        I0[3] = __builtin_nontemporal_load(r + 3);
    }
    if (v1) {
        const v4i* r = (const v4i*)(knn + (size_t)p1 * 16);
        I1[0] = __builtin_nontemporal_load(r + 0);
        I1[1] = __builtin_nontemporal_load(r + 1);
        I1[2] = __builtin_nontemporal_load(r + 2);
        I1[3] = __builtin_nontemporal_load(r + 3);
    }

    float sd0 = 0.f, sq0 = 0.f, sd1 = 0.f, sq1 = 0.f;

    for (int c = 0; c < nc; ++c) {
        #pragma unroll
        for (int q = 0; q < 4; ++q) {
            proc_gather_q(I0[q].x, c, cshift, NH0, sd0, sq0, xyzq);
            proc_gather_q(I0[q].y, c, cshift, NH0, sd0, sq0, xyzq);
            proc_gather_q(I0[q].z, c, cshift, NH0, sd0, sq0, xyzq);
            proc_gather_q(I0[q].w, c, cshift, NH0, sd0, sq0, xyzq);
            proc_gather_q(I1[q].x, c, cshift, NH1, sd1, sq1, xyzq);
            proc_gather_q(I1[q].y, c, cshift, NH1, sd1, sq1, xyzq);
            proc_gather_q(I1[q].z, c, cshift, NH1, sd1, sq1, xyzq);
            proc_gather_q(I1[q].w, c, cshift, NH1, sd1, sq1, xyzq);
        }
    }
    if (v0) s_var += sq0 - sd0 * sd0 * (1.f/16.f);
    if (v1) s_var += sq1 - sd1 * sd1 * (1.f/16.f);

    block_reduce_atomic3(0.f, s_var, 0.f, acc);
}

// ---------------------------------------------------------------------------
// Fallback: known-good monolithic kernel (round 2) if ws too small
// ---------------------------------------------------------------------------
__global__ __launch_bounds__(256) void align_direct(
    const float* __restrict__ xyz,
    const float* __restrict__ scales,
    const float* __restrict__ rotation,
    const int*   __restrict__ knn,
    const float* __restrict__ normal,
    double* __restrict__ acc,
    int n)
{
    float s_min = 0.f, s_var = 0.f, s_nrm = 0.f;
    const int stride = gridDim.x * blockDim.x;
    for (int i = blockIdx.x * blockDim.x + threadIdx.x; i < n; i += stride) {
        float omin, onrm, nx, ny, nz, pd;
        point_stream_math(xyz[3*(size_t)i], xyz[3*(size_t)i+1], xyz[3*(size_t)i+2],
                          normal[3*(size_t)i], normal[3*(size_t)i+1], normal[3*(size_t)i+2],
                          scales[3*(size_t)i], scales[3*(size_t)i+1], scales[3*(size_t)i+2],
                          rotation[4*(size_t)i], rotation[4*(size_t)i+1],
                          rotation[4*(size_t)i+2], rotation[4*(size_t)i+3],
                          omin, onrm, nx, ny, nz, pd);
        s_min += omin; s_nrm += onrm;

        const int4* krow = (const int4*)(knn + (size_t)16 * i);
        float sum_d = 0.f, sum_d2 = 0.f;
        #pragma unroll
        for (int q = 0; q < 4; ++q) {
            const int4 j4 = krow[q];
            const int js[4] = { j4.x, j4.y, j4.z, j4.w };
            #pragma unroll
            for (int u = 0; u < 4; ++u) {
                const size_t j = (size_t)js[u] * 3;
                const float d = xyz[j]*nx + xyz[j+1]*ny + xyz[j+2]*nz - pd;
                sum_d  += d; sum_d2 += d*d;
            }
        }
        s_var += sum_d2 - sum_d * sum_d * (1.f/16.f);
    }
    block_reduce_atomic3(s_min, s_var, s_nrm, acc);
}

__global__ void align_finalize(const double* __restrict__ acc,
                               float* __restrict__ out, int n)
{
    if (threadIdx.x == 0) {
        out[0] = (float)(acc[ACC_MIN] / (double)n);
        out[1] = (float)(acc[ACC_VAR] / ((double)n * 16.0));
        out[2] = (float)(acc[ACC_NRM] / (double)n);
    }
}

extern "C" void kernel_launch(void* const* d_in, const int* in_sizes, int n_in,
                              void* d_out, int out_size, void* d_ws, size_t ws_size,
                              hipStream_t stream) {
    const float* xyz      = (const float*)d_in[0];
    const float* scales   = (const float*)d_in[2];
    const float* rotation = (const float*)d_in[3];
    const int*   knn      = (const int*)d_in[4];
    const float* normal   = (const float*)d_in[5];
    float* out = (float*)d_out;

    const int n = in_sizes[1];  // xyz_id count == N

    // layout: xyzq (4B*n) | nhat4 (16B*n) | acc (64 doubles)
    const size_t need = (size_t)n * 20 + 64 * sizeof(double);
    if (ws_size >= need) {
        unsigned* xyzq  = (unsigned*)d_ws;
        float4*   nhat4 = (float4*)((char*)d_ws + (size_t)n * 4);
        double*   acc   = (double*)((char*)d_ws + (size_t)n * 20);

        hipMemsetAsync(acc, 0, 33 * sizeof(double), stream);

        const int ntask = n >> 2;
        int pgrid = (ntask + 255) / 256;
        if (pgrid > 2048) pgrid = 2048;
        align_pack<<<pgrid, 256, 0, stream>>>(xyz, scales, rotation, normal,
                                              xyzq, nhat4, acc, n);

        // 2MB chunks of the 4B-quantized position array = 512K points
        const int cshift = 19;
        const int nc = ((n - 1) >> cshift) + 1;

        const int ggrid = (n + 511) / 512;   // 2 points per thread
        align_gather_q<<<ggrid, 256, 0, stream>>>(xyzq, nhat4, knn, acc,
                                                  n, cshift, nc);
        align_finalize<<<1, 64, 0, stream>>>(acc, out, n);
    } else {
        double* acc = (double*)d_ws;
        hipMemsetAsync(acc, 0, 33 * sizeof(double), stream);
        int grid = (n + 255) / 256;
        if (grid > 2048) grid = 2048;
        align_direct<<<grid, 256, 0, stream>>>(xyz, scales, rotation, knn, normal, acc, n);
        align_finalize<<<1, 64, 0, stream>>>(acc, out, n);
    }
}

// Round 7
// 494.175 us; speedup vs baseline: 1.8937x; 1.1019x over previous
//
#include <hip/hip_runtime.h>
#include <math.h>

#define EPSF 1e-8f

// acc doubles in workspace, padded onto separate cache lines
#define ACC_MIN 0
#define ACC_VAR 16
#define ACC_NRM 32

typedef int   v4i __attribute__((ext_vector_type(4)));
typedef float v4f __attribute__((ext_vector_type(4)));

// ---------------------------------------------------------------------------
// block reduction helper: wave64 shuffle + LDS + double atomics
// ---------------------------------------------------------------------------
__device__ __forceinline__ void block_reduce_atomic3(
    float a, float b, float c, double* acc)
{
    #pragma unroll
    for (int off = 32; off > 0; off >>= 1) {
        a += __shfl_down(a, off);
        b += __shfl_down(b, off);
        c += __shfl_down(c, off);
    }
    __shared__ float red[3][4];
    const int lane = threadIdx.x & 63;
    const int wave = threadIdx.x >> 6;
    if (lane == 0) { red[0][wave] = a; red[1][wave] = b; red[2][wave] = c; }
    __syncthreads();
    if (threadIdx.x == 0) {
        double x = 0, y = 0, z = 0;
        #pragma unroll
        for (int wv = 0; wv < 4; ++wv) { x += red[0][wv]; y += red[1][wv]; z += red[2][wv]; }
        if (x != 0.0) atomicAdd(&acc[ACC_MIN], x);
        if (y != 0.0) atomicAdd(&acc[ACC_VAR], y);
        if (z != 0.0) atomicAdd(&acc[ACC_NRM], z);
    }
}

// ---------------------------------------------------------------------------
// per-point streaming math
// ---------------------------------------------------------------------------
__device__ __forceinline__ void point_stream_math(
    float px, float py, float pz,
    float nx, float ny, float nz,
    float s0, float s1, float s2,
    float qw, float qx, float qy, float qz,
    float& out_min, float& out_nrm,
    float& onx, float& ony, float& onz, float& opd)
{
    const float ninv = 1.f / (sqrtf(nx*nx + ny*ny + nz*nz) + EPSF);
    nx *= ninv; ny *= ninv; nz *= ninv;

    out_min = fminf(s0, fminf(s1, s2));
    const int min_idx = (s0 <= s1 && s0 <= s2) ? 0 : ((s1 <= s2) ? 1 : 2);

    const float qinv = 1.f / (sqrtf(qw*qw + qx*qx + qy*qy + qz*qz) + EPSF);
    const float w = qw*qinv, x = qx*qinv, y = qy*qinv, z = qz*qinv;
    float ax, ay, az;
    if (min_idx == 0) {
        ax = 1.f - 2.f*(y*y + z*z); ay = 2.f*(x*y + w*z); az = 2.f*(x*z - w*y);
    } else if (min_idx == 1) {
        ax = 2.f*(x*y - w*z); ay = 1.f - 2.f*(x*x + z*z); az = 2.f*(y*z + w*x);
    } else {
        ax = 2.f*(x*z + w*y); ay = 2.f*(y*z - w*x); az = 1.f - 2.f*(x*x + y*y);
    }
    out_nrm = 1.f - fabsf(ax*nx + ay*ny + az*nz);

    onx = nx; ony = ny; onz = nz;
    opd = px*nx + py*ny + pz*nz;
}

__device__ __forceinline__ unsigned quant_point(float px, float py, float pz)
{
    int qx = __float2int_rn(px * 64.f);
    int qy = __float2int_rn(py * 64.f);
    int qz = __float2int_rn(pz * 64.f);
    qx = min(511, max(-512, qx));
    qy = min(511, max(-512, qy));
    qz = min(511, max(-512, qz));
    return (unsigned)(qx & 1023) | ((unsigned)(qy & 1023) << 10)
         | ((unsigned)(qz & 1023) << 20);
}

// ---------------------------------------------------------------------------
// Prepass: quantize xyz -> 10/10/10 fixed point (4B, scale 1/64),
// nhat4 = (n̂/64, p·n̂), accumulate loss_size / loss_normal sums.
// ---------------------------------------------------------------------------
__global__ __launch_bounds__(256) void align_pack(
    const float* __restrict__ xyz,
    const float* __restrict__ scales,
    const float* __restrict__ rotation,
    const float* __restrict__ normal,
    unsigned* __restrict__ xyzq,
    float4*   __restrict__ nhat4,
    double*   __restrict__ acc,
    int n)
{
    float s_min = 0.f, s_nrm = 0.f;
    const int ntask = n >> 2;              // 4 points per task
    const int stride = gridDim.x * blockDim.x;
    const int tid0 = blockIdx.x * blockDim.x + threadIdx.x;

    for (int tsk = tid0; tsk < ntask; tsk += stride) {
        const int i0 = tsk * 4;
        const float4* xv = (const float4*)(xyz    + (size_t)i0*3);
        const float4* sv = (const float4*)(scales + (size_t)i0*3);
        const float4* nv = (const float4*)(normal + (size_t)i0*3);
        const float4* qv = (const float4*)(rotation + (size_t)i0*4);
        const float4 xa = xv[0], xb = xv[1], xc = xv[2];
        const float4 sa = sv[0], sb = sv[1], sc = sv[2];
        const float4 na = nv[0], nb = nv[1], nc4 = nv[2];

        const float PX[4] = {xa.x, xa.w, xb.z, xc.y};
        const float PY[4] = {xa.y, xb.x, xb.w, xc.z};
        const float PZ[4] = {xa.z, xb.y, xc.x, xc.w};
        const float S0[4] = {sa.x, sa.w, sb.z, sc.y};
        const float S1[4] = {sa.y, sb.x, sb.w, sc.z};
        const float S2[4] = {sa.z, sb.y, sc.x, sc.w};
        const float NX[4] = {na.x, na.w, nb.z, nc4.y};
        const float NY[4] = {na.y, nb.x, nb.w, nc4.z};
        const float NZ[4] = {na.z, nb.y, nc4.x, nc4.w};

        #pragma unroll
        for (int m = 0; m < 4; ++m) {
            const float4 q = qv[m];
            float omin, onrm, nx, ny, nz, pd;
            point_stream_math(PX[m], PY[m], PZ[m], NX[m], NY[m], NZ[m],
                              S0[m], S1[m], S2[m], q.x, q.y, q.z, q.w,
                              omin, onrm, nx, ny, nz, pd);
            s_min += omin; s_nrm += onrm;
            xyzq[i0 + m]  = quant_point(PX[m], PY[m], PZ[m]);
            nhat4[i0 + m] = make_float4(nx * (1.f/64.f), ny * (1.f/64.f),
                                        nz * (1.f/64.f), pd);
        }
    }

    // scalar tail (n not divisible by 4)
    if (tid0 == 0) {
        for (int i = ntask*4; i < n; ++i) {
            float omin, onrm, nx, ny, nz, pd;
            point_stream_math(xyz[3*(size_t)i], xyz[3*(size_t)i+1], xyz[3*(size_t)i+2],
                              normal[3*(size_t)i], normal[3*(size_t)i+1], normal[3*(size_t)i+2],
                              scales[3*(size_t)i], scales[3*(size_t)i+1], scales[3*(size_t)i+2],
                              rotation[4*(size_t)i], rotation[4*(size_t)i+1],
                              rotation[4*(size_t)i+2], rotation[4*(size_t)i+3],
                              omin, onrm, nx, ny, nz, pd);
            s_min += omin; s_nrm += onrm;
            xyzq[i]  = quant_point(xyz[3*(size_t)i], xyz[3*(size_t)i+1], xyz[3*(size_t)i+2]);
            nhat4[i] = make_float4(nx * (1.f/64.f), ny * (1.f/64.f),
                                   nz * (1.f/64.f), pd);
        }
    }

    block_reduce_atomic3(s_min, 0.f, s_nrm, acc);
}

// ---------------------------------------------------------------------------
// Chunked gather: 2 chunks x 4MB, each exactly one XCD-L2.
// 2 points/thread; 32 knn indices live in VGPRs across the 2 chunk passes.
// Flat grid; blocks stay naturally in-phase.
// ---------------------------------------------------------------------------
__device__ __forceinline__ void proc_gather_q(
    int j, int c, int cshift, const float4 nh,
    float& sd, float& sq, const unsigned* __restrict__ xyzq)
{
    if ((j >> cshift) == c) {            // -1 padding never matches
        const int w = (int)xyzq[j];
        const float fx = (float)((w << 22) >> 22);
        const float fy = (float)((w << 12) >> 22);
        const float fz = (float)((w <<  2) >> 22);
        const float d = fx*nh.x + fy*nh.y + fz*nh.z - nh.w;
        sd += d; sq += d*d;
    }
}

__global__ __launch_bounds__(256) void align_gather_q(
    const unsigned* __restrict__ xyzq,
    const float4*   __restrict__ nhat4,
    const int*      __restrict__ knn,
    double* __restrict__ acc,
    int n, int cshift, int nc)
{
    const int t = blockIdx.x * blockDim.x + threadIdx.x;
    const int p0 = t * 2;
    const int p1 = p0 + 1;
    const bool v0 = p0 < n, v1 = p1 < n;
    float s_var = 0.f;

    const v4f z4 = {0.f, 0.f, 0.f, 0.f};
    v4f nh0 = z4, nh1 = z4;
    if (v0) nh0 = __builtin_nontemporal_load((const v4f*)(nhat4 + p0));
    if (v1) nh1 = __builtin_nontemporal_load((const v4f*)(nhat4 + p1));
    const float4 NH0 = make_float4(nh0.x, nh0.y, nh0.z, nh0.w);
    const float4 NH1 = make_float4(nh1.x, nh1.y, nh1.z, nh1.w);

    v4i I0[4], I1[4];
    const v4i inval = {-1, -1, -1, -1};
    #pragma unroll
    for (int q = 0; q < 4; ++q) { I0[q] = inval; I1[q] = inval; }
    if (v0) {
        const v4i* r = (const v4i*)(knn + (size_t)p0 * 16);
        I0[0] = __builtin_nontemporal_load(r + 0);
        I0[1] = __builtin_nontemporal_load(r + 1);
        I0[2] = __builtin_nontemporal_load(r + 2);
        I0[3] = __builtin_nontemporal_load(r + 3);
    }
    if (v1) {
        const v4i* r = (const v4i*)(knn + (size_t)p1 * 16);
        I1[0] = __builtin_nontemporal_load(r + 0);
        I1[1] = __builtin_nontemporal_load(r + 1);
        I1[2] = __builtin_nontemporal_load(r + 2);
        I1[3] = __builtin_nontemporal_load(r + 3);
    }

    float sd0 = 0.f, sq0 = 0.f, sd1 = 0.f, sq1 = 0.f;

    for (int c = 0; c < nc; ++c) {
        #pragma unroll
        for (int q = 0; q < 4; ++q) {
            proc_gather_q(I0[q].x, c, cshift, NH0, sd0, sq0, xyzq);
            proc_gather_q(I0[q].y, c, cshift, NH0, sd0, sq0, xyzq);
            proc_gather_q(I0[q].z, c, cshift, NH0, sd0, sq0, xyzq);
            proc_gather_q(I0[q].w, c, cshift, NH0, sd0, sq0, xyzq);
            proc_gather_q(I1[q].x, c, cshift, NH1, sd1, sq1, xyzq);
            proc_gather_q(I1[q].y, c, cshift, NH1, sd1, sq1, xyzq);
            proc_gather_q(I1[q].z, c, cshift, NH1, sd1, sq1, xyzq);
            proc_gather_q(I1[q].w, c, cshift, NH1, sd1, sq1, xyzq);
        }
    }
    if (v0) s_var += sq0 - sd0 * sd0 * (1.f/16.f);
    if (v1) s_var += sq1 - sd1 * sd1 * (1.f/16.f);

    block_reduce_atomic3(0.f, s_var, 0.f, acc);
}

// ---------------------------------------------------------------------------
// Fallback: known-good monolithic kernel (round 2) if ws too small
// ---------------------------------------------------------------------------
__global__ __launch_bounds__(256) void align_direct(
    const float* __restrict__ xyz,
    const float* __restrict__ scales,
    const float* __restrict__ rotation,
    const int*   __restrict__ knn,
    const float* __restrict__ normal,
    double* __restrict__ acc,
    int n)
{
    float s_min = 0.f, s_var = 0.f, s_nrm = 0.f;
    const int stride = gridDim.x * blockDim.x;
    for (int i = blockIdx.x * blockDim.x + threadIdx.x; i < n; i += stride) {
        float omin, onrm, nx, ny, nz, pd;
        point_stream_math(xyz[3*(size_t)i], xyz[3*(size_t)i+1], xyz[3*(size_t)i+2],
                          normal[3*(size_t)i], normal[3*(size_t)i+1], normal[3*(size_t)i+2],
                          scales[3*(size_t)i], scales[3*(size_t)i+1], scales[3*(size_t)i+2],
                          rotation[4*(size_t)i], rotation[4*(size_t)i+1],
                          rotation[4*(size_t)i+2], rotation[4*(size_t)i+3],
                          omin, onrm, nx, ny, nz, pd);
        s_min += omin; s_nrm += onrm;

        const int4* krow = (const int4*)(knn + (size_t)16 * i);
        float sum_d = 0.f, sum_d2 = 0.f;
        #pragma unroll
        for (int q = 0; q < 4; ++q) {
            const int4 j4 = krow[q];
            const int js[4] = { j4.x, j4.y, j4.z, j4.w };
            #pragma unroll
            for (int u = 0; u < 4; ++u) {
                const size_t j = (size_t)js[u] * 3;
                const float d = xyz[j]*nx + xyz[j+1]*ny + xyz[j+2]*nz - pd;
                sum_d  += d; sum_d2 += d*d;
            }
        }
        s_var += sum_d2 - sum_d * sum_d * (1.f/16.f);
    }
    block_reduce_atomic3(s_min, s_var, s_nrm, acc);
}

__global__ void align_finalize(const double* __restrict__ acc,
                               float* __restrict__ out, int n)
{
    if (threadIdx.x == 0) {
        out[0] = (float)(acc[ACC_MIN] / (double)n);
        out[1] = (float)(acc[ACC_VAR] / ((double)n * 16.0));
        out[2] = (float)(acc[ACC_NRM] / (double)n);
    }
}

extern "C" void kernel_launch(void* const* d_in, const int* in_sizes, int n_in,
                              void* d_out, int out_size, void* d_ws, size_t ws_size,
                              hipStream_t stream) {
    const float* xyz      = (const float*)d_in[0];
    const float* scales   = (const float*)d_in[2];
    const float* rotation = (const float*)d_in[3];
    const int*   knn      = (const int*)d_in[4];
    const float* normal   = (const float*)d_in[5];
    float* out = (float*)d_out;

    const int n = in_sizes[1];  // xyz_id count == N

    // layout: xyzq (4B*n) | nhat4 (16B*n) | acc (64 doubles)
    const size_t need = (size_t)n * 20 + 64 * sizeof(double);
    if (ws_size >= need) {
        unsigned* xyzq  = (unsigned*)d_ws;
        float4*   nhat4 = (float4*)((char*)d_ws + (size_t)n * 4);
        double*   acc   = (double*)((char*)d_ws + (size_t)n * 20);

        hipMemsetAsync(acc, 0, 33 * sizeof(double), stream);

        const int ntask = n >> 2;
        int pgrid = (ntask + 255) / 256;
        if (pgrid > 2048) pgrid = 2048;
        align_pack<<<pgrid, 256, 0, stream>>>(xyz, scales, rotation, normal,
                                              xyzq, nhat4, acc, n);

        // 4MB chunks of the 4B-quantized position array = 1M points
        // (one full XCD-L2 per chunk; 2 passes for n=2M)
        const int cshift = 20;
        const int nc = ((n - 1) >> cshift) + 1;

        const int ggrid = (n + 511) / 512;   // 2 points per thread
        align_gather_q<<<ggrid, 256, 0, stream>>>(xyzq, nhat4, knn, acc,
                                                  n, cshift, nc);
        align_finalize<<<1, 64, 0, stream>>>(acc, out, n);
    } else {
        double* acc = (double*)d_ws;
        hipMemsetAsync(acc, 0, 33 * sizeof(double), stream);
        int grid = (n + 255) / 256;
        if (grid > 2048) grid = 2048;
        align_direct<<<grid, 256, 0, stream>>>(xyz, scales, rotation, knn, normal, acc, n);
        align_finalize<<<1, 64, 0, stream>>>(acc, out, n);
    }
}